// Round 3
// baseline (705.901 us; speedup 1.0000x reference)
//
#include <hip/hip_runtime.h>
#include <hip/hip_bf16.h>
#include <math.h>

#define B_DIM 4096
#define D_IN  2048
#define D_HID 3584
#define D_OUT 2048

typedef __bf16 bf16;
typedef float  floatx4 __attribute__((ext_vector_type(4)));
typedef bf16   bf16x8  __attribute__((ext_vector_type(8)));

typedef __attribute__((address_space(1))) const void* gptr1;
typedef __attribute__((address_space(3))) void*       lptr3;

__device__ __forceinline__ void load_lds16(const void* g, void* l) {
    __builtin_amdgcn_global_load_lds((gptr1)g, (lptr3)l, 16, 0, 0);
}

struct HL { bf16 h, l; };
__device__ __forceinline__ HL split2(float v) {
    HL r;
    r.h = (bf16)v;
    r.l = (bf16)(v - (float)r.h);
    return r;
}

// ---------------------------------------------------------------------------
// Vesica (fp32 in): x_overlap = x * (1 + relu(1 - |dist - 1|)); emit bf16 hi/lo
// one block per row; thread owns 8 contiguous fp32.
// ---------------------------------------------------------------------------
__global__ __launch_bounds__(256) void vesica_kernel(const float* __restrict__ x,
                                                     bf16* __restrict__ xh,
                                                     bf16* __restrict__ xl) {
    const int b  = blockIdx.x;
    const int bp = (b == 0) ? (B_DIM - 1) : (b - 1);
    const int t  = threadIdx.x;

    const floatx4* xr = (const floatx4*)(x + (size_t)b  * D_IN);
    const floatx4* pr = (const floatx4*)(x + (size_t)bp * D_IN);
    const floatx4 v0 = xr[t * 2], v1 = xr[t * 2 + 1];
    const floatx4 p0 = pr[t * 2], p1 = pr[t * 2 + 1];

    float s = 0.f;
#pragma unroll
    for (int j = 0; j < 4; ++j) {
        const float d0 = v0[j] - p0[j], d1 = v1[j] - p1[j];
        s += d0 * d0 + d1 * d1;
    }
#pragma unroll
    for (int off = 32; off > 0; off >>= 1) s += __shfl_down(s, off, 64);

    __shared__ float red[4];
    const int wave = t >> 6, lane = t & 63;
    if (lane == 0) red[wave] = s;
    __syncthreads();
    const float dist = sqrtf(red[0] + red[1] + red[2] + red[3]);
    const float sc   = 1.f + fmaxf(0.f, 1.f - fabsf(dist - 1.f));

    bf16x8 h, l;
#pragma unroll
    for (int j = 0; j < 4; ++j) {
        const HL a = split2(v0[j] * sc);
        const HL b2 = split2(v1[j] * sc);
        h[j] = a.h;     l[j] = a.l;
        h[4 + j] = b2.h; l[4 + j] = b2.l;
    }
    ((bf16x8*)(xh + (size_t)b * D_IN))[t] = h;
    ((bf16x8*)(xl + (size_t)b * D_IN))[t] = l;
}

// ---------------------------------------------------------------------------
// Split fp32 weight array into bf16 hi/lo. One thread = 8 elements.
// ---------------------------------------------------------------------------
__global__ __launch_bounds__(256) void split_kernel(const float* __restrict__ w,
                                                    bf16* __restrict__ wh,
                                                    bf16* __restrict__ wl) {
    const size_t i = (size_t)blockIdx.x * 256 + threadIdx.x;
    const floatx4 a = ((const floatx4*)w)[i * 2];
    const floatx4 b = ((const floatx4*)w)[i * 2 + 1];
    bf16x8 h, l;
#pragma unroll
    for (int j = 0; j < 4; ++j) {
        const HL u = split2(a[j]);
        const HL v = split2(b[j]);
        h[j] = u.h;     l[j] = u.l;
        h[4 + j] = v.h; l[4 + j] = v.l;
    }
    ((bf16x8*)wh)[i] = h;
    ((bf16x8*)wl)[i] = l;
}

// ---------------------------------------------------------------------------
// Flip W_female [2048,3584] along axis 1, split into bf16 hi/lo.
// ---------------------------------------------------------------------------
__global__ __launch_bounds__(256) void flipsplit_kernel(const float* __restrict__ w,
                                                        bf16* __restrict__ wh,
                                                        bf16* __restrict__ wl) {
    const int i = blockIdx.x * 256 + threadIdx.x; // output 8-group id
    const int o = i / 448;
    const int g = i - o * 448;
    const float* src = w + (size_t)o * 3584 + (size_t)(447 - g) * 8;
    const floatx4 a = ((const floatx4*)src)[0];
    const floatx4 b = ((const floatx4*)src)[1];
    // out[j] = src[7-j]
    bf16x8 h, l;
#pragma unroll
    for (int j = 0; j < 4; ++j) {
        const HL u = split2(b[3 - j]);   // out[0..3] = src[7..4]
        const HL v = split2(a[3 - j]);   // out[4..7] = src[3..0]
        h[j] = u.h;     l[j] = u.l;
        h[4 + j] = v.h; l[4 + j] = v.l;
    }
    ((bf16x8*)wh)[(size_t)o * 448 + g] = h;
    ((bf16x8*)wl)[(size_t)o * 448 + g] = l;
}

// ---------------------------------------------------------------------------
// bf16x3 split-precision GEMM  C[M,N] = A[M,K] * B[N,K]^T
//   C ≈ Ah·Bh + Al·Bh + Ah·Bl  (fp32 accumulate) — ~17 mantissa bits
// 128x128 tile, BK=32, 4 waves (2x2), each wave 4x4 of 16x16x32 bf16 MFMAs.
// OUT_MODE 1: flower — phase multiply, write bf16 hi/lo (C0/C1)
// OUT_MODE 2: write fp32 to C0
// ---------------------------------------------------------------------------
template <int OUT_MODE>
__global__ __launch_bounds__(256) void gemm3_bt(const bf16* __restrict__ Ah,
                                                const bf16* __restrict__ Al,
                                                const bf16* __restrict__ Bh,
                                                const bf16* __restrict__ Bl,
                                                void* __restrict__ C0,
                                                void* __restrict__ C1,
                                                int M, int N, int K) {
    __shared__ bf16 sAh[128 * 32];
    __shared__ bf16 sAl[128 * 32];
    __shared__ bf16 sBh[128 * 32];
    __shared__ bf16 sBl[128 * 32];

    const int tid  = threadIdx.x;
    const int wave = tid >> 6;
    const int lane = tid & 63;
    const int m0   = blockIdx.y * 128;
    const int n0   = blockIdx.x * 128;
    const int wm   = wave & 1;
    const int wn   = wave >> 1;

    floatx4 acc[4][4];
#pragma unroll
    for (int i = 0; i < 4; ++i)
#pragma unroll
        for (int j = 0; j < 4; ++j) acc[i][j] = (floatx4){0.f, 0.f, 0.f, 0.f};

    const int lr = lane & 15;
    const int lk = (lane >> 4) << 3;

    for (int kt = 0; kt < K; kt += 32) {
#pragma unroll
        for (int i = 0; i < 2; ++i) {
            const int e   = ((i * 4 + wave) << 9) + (lane << 3);
            const int row = e >> 5;
            const int col = e & 31;
            const size_t ga = (size_t)(m0 + row) * K + kt + col;
            const size_t gb = (size_t)(n0 + row) * K + kt + col;
            load_lds16(&Ah[ga], &sAh[e]);
            load_lds16(&Al[ga], &sAl[e]);
            load_lds16(&Bh[gb], &sBh[e]);
            load_lds16(&Bl[gb], &sBl[e]);
        }
        __syncthreads();

        bf16x8 ah[4], al[4], bh[4], bl[4];
#pragma unroll
        for (int mi = 0; mi < 4; ++mi) {
            const int off = ((wm * 64 + mi * 16 + lr) << 5) + lk;
            ah[mi] = *(const bf16x8*)&sAh[off];
            al[mi] = *(const bf16x8*)&sAl[off];
        }
#pragma unroll
        for (int ni = 0; ni < 4; ++ni) {
            const int off = ((wn * 64 + ni * 16 + lr) << 5) + lk;
            bh[ni] = *(const bf16x8*)&sBh[off];
            bl[ni] = *(const bf16x8*)&sBl[off];
        }

#pragma unroll
        for (int mi = 0; mi < 4; ++mi)
#pragma unroll
            for (int ni = 0; ni < 4; ++ni) {
                acc[mi][ni] = __builtin_amdgcn_mfma_f32_16x16x32_bf16(
                    ah[mi], bh[ni], acc[mi][ni], 0, 0, 0);
                acc[mi][ni] = __builtin_amdgcn_mfma_f32_16x16x32_bf16(
                    al[mi], bh[ni], acc[mi][ni], 0, 0, 0);
                acc[mi][ni] = __builtin_amdgcn_mfma_f32_16x16x32_bf16(
                    ah[mi], bl[ni], acc[mi][ni], 0, 0, 0);
            }
        __syncthreads();
    }

    // epilogue: C/D layout col = lane&15, row = (lane>>4)*4 + r
    const int rq = (lane >> 4) << 2;
    const int cl = lane & 15;
#pragma unroll
    for (int mi = 0; mi < 4; ++mi) {
#pragma unroll
        for (int ni = 0; ni < 4; ++ni) {
            const int col = n0 + wn * 64 + ni * 16 + cl;
            float pm = 1.0f;
            if (OUT_MODE == 1) {
                const int jm = col & 511;
                if (jm < 2) {
                    const float ph = 0.8975979010256552f * (float)(col >> 9); // 2pi/7*c
                    pm = (jm == 0) ? cosf(ph) : sinf(ph);
                }
            }
#pragma unroll
            for (int r = 0; r < 4; ++r) {
                const int row = m0 + wm * 64 + mi * 16 + rq + r;
                const size_t idx = (size_t)row * N + col;
                float v = acc[mi][ni][r];
                if (OUT_MODE == 1) {
                    v *= pm;
                    const HL u = split2(v);
                    ((bf16*)C0)[idx] = u.h;
                    ((bf16*)C1)[idx] = u.l;
                } else {
                    ((float*)C0)[idx] = v;
                }
            }
        }
    }
}

// ---------------------------------------------------------------------------
// Combine: phase_lock = sigmoid(male . female); out = pl*male + (1-pl)*female
// fp32 in, fp32 out. one block per row.
// ---------------------------------------------------------------------------
__global__ __launch_bounds__(256) void combine_kernel(const float* __restrict__ male,
                                                      const float* __restrict__ female,
                                                      float* __restrict__ out) {
    const int b = blockIdx.x;
    const int t = threadIdx.x;

    const floatx4* m4 = (const floatx4*)(male   + (size_t)b * D_OUT);
    const floatx4* f4 = (const floatx4*)(female + (size_t)b * D_OUT);
    const floatx4 mv0 = m4[t * 2], mv1 = m4[t * 2 + 1];
    const floatx4 fv0 = f4[t * 2], fv1 = f4[t * 2 + 1];

    float s = 0.f;
#pragma unroll
    for (int j = 0; j < 4; ++j) s += mv0[j] * fv0[j] + mv1[j] * fv1[j];
#pragma unroll
    for (int off = 32; off > 0; off >>= 1) s += __shfl_down(s, off, 64);

    __shared__ float red[4];
    const int wave = t >> 6, lane = t & 63;
    if (lane == 0) red[wave] = s;
    __syncthreads();
    const float dot = red[0] + red[1] + red[2] + red[3];
    const float pl  = 1.f / (1.f + expf(-dot));

    floatx4 o0, o1;
#pragma unroll
    for (int j = 0; j < 4; ++j) {
        o0[j] = pl * mv0[j] + (1.f - pl) * fv0[j];
        o1[j] = pl * mv1[j] + (1.f - pl) * fv1[j];
    }
    floatx4* o4 = (floatx4*)(out + (size_t)b * D_OUT);
    o4[t * 2]     = o0;
    o4[t * 2 + 1] = o1;
}

// ---------------------------------------------------------------------------
extern "C" void kernel_launch(void* const* d_in, const int* in_sizes, int n_in,
                              void* d_out, int out_size, void* d_ws, size_t ws_size,
                              hipStream_t stream) {
    const float* x   = (const float*)d_in[0];
    const float* Wfl = (const float*)d_in[1]; // [7,512,2048] == [3584,2048]
    const float* Wm  = (const float*)d_in[2]; // [2048,3584]
    const float* Wfe = (const float*)d_in[3]; // [2048,3584]
    float* out = (float*)d_out;
    (void)in_sizes; (void)n_in; (void)out_size; (void)ws_size;

    char* ws = (char*)d_ws;
    bf16*  xe_hi  = (bf16*)(ws);                    // 4096x3584 bf16 = 29,360,128
    bf16*  xe_lo  = (bf16*)(ws + 29360128);         // 29,360,128
    float* male   = (float*)(ws + 58720256);        // 4096x2048 f32 = 33,554,432
    float* female = (float*)(ws + 92274688);        // 33,554,432
    // phase-1 region (dead after flower GEMM):
    bf16*  xo_hi  = (bf16*)(ws + 125829120);        // 16,777,216
    bf16*  xo_lo  = (bf16*)(ws + 142606336);        // 16,777,216
    bf16*  Wfl_hi = (bf16*)(ws + 159383552);        // 14,680,064
    bf16*  Wfl_lo = (bf16*)(ws + 174063616);        // end 188,743,680
    // phase-2 overlay of the same region:
    bf16*  Wm_hi  = (bf16*)(ws + 125829120);
    bf16*  Wm_lo  = (bf16*)(ws + 140509184);
    bf16*  Wff_hi = (bf16*)(ws + 155189248);
    bf16*  Wff_lo = (bf16*)(ws + 169869312);        // end 184,549,376

    // 1. vesica scaling (fp32 -> bf16 hi/lo)
    vesica_kernel<<<B_DIM, 256, 0, stream>>>(x, xo_hi, xo_lo);

    // 2. split W_flower
    split_kernel<<<(D_HID * D_IN / 8) / 256, 256, 0, stream>>>(Wfl, Wfl_hi, Wfl_lo);

    // 3. flower GEMM (bf16x3) + phase epilogue -> xe hi/lo [4096,3584]
    gemm3_bt<1><<<dim3(D_HID / 128, B_DIM / 128), 256, 0, stream>>>(
        xo_hi, xo_lo, Wfl_hi, Wfl_lo, (void*)xe_hi, (void*)xe_lo, B_DIM, D_HID, D_IN);

    // 4. split W_male; flip+split W_female (overlays dead phase-1 region)
    split_kernel<<<(D_OUT * D_HID / 8) / 256, 256, 0, stream>>>(Wm, Wm_hi, Wm_lo);
    flipsplit_kernel<<<(D_OUT * (D_HID / 8)) / 256, 256, 0, stream>>>(Wfe, Wff_hi, Wff_lo);

    // 5. male / female GEMMs (bf16x3, fp32 out)
    gemm3_bt<2><<<dim3(D_OUT / 128, B_DIM / 128), 256, 0, stream>>>(
        xe_hi, xe_lo, Wm_hi, Wm_lo, (void*)male, nullptr, B_DIM, D_OUT, D_HID);
    gemm3_bt<2><<<dim3(D_OUT / 128, B_DIM / 128), 256, 0, stream>>>(
        xe_hi, xe_lo, Wff_hi, Wff_lo, (void*)female, nullptr, B_DIM, D_OUT, D_HID);

    // 6. sigmoid phase-lock blend (fp32 out)
    combine_kernel<<<B_DIM, 256, 0, stream>>>(male, female, out);
}